// Round 14
// baseline (3725.687 us; speedup 1.0000x reference)
//
#include <hip/hip_runtime.h>
#include <hip/hip_bf16.h>

#define BB 32
#define SS 64
#define TT 64
#define EE 512
#define HH 512
#define VV 32000

// ---- ws float offsets ----
#define O_C0    0u          // enc c parity0 [2dir][32][512]
#define O_C1    32768u      // enc c parity1
#define O_PENC  131072u     // enc partials parity A [dir][kp4][32b][2048]
#define O_PDEC  655360u     // enc partials parity B; dec partials [kp4][32][4096]
#define O_HD    65536u      // dec h [32][1024]
#define O_CD    98304u      // dec c
#define O_ALLH  1212416u    // all_hidden [32][64][1024]; later A1 (f16 hi)
#define O_AATT  3309568u    // A-attn [32][64][1024];    later A2 (f16 lo*2048)
#define O_HDEC  5406720u    // decoder hidden [32][64][1024]
#define O_PACK  7503872u    // 2048 u64 argmax packed
#define O_DA1   7507968u    // dec act f16 hi  [32][2048] (as f16)
#define O_DA2   7540736u    // dec act f16 lo*2048
#define O_W1    7573504u    // Wout f16 [32000][1024] (as f16) -- needs big ws
#define WS_NEED 95830016ull // bytes

// ---- d_out f32-scratch offsets (dead before k_logits) ----
#define S_GXF   0u          // [64][32][2048]
#define S_GXB   4194304u
#define S_GFEED 8388608u    // [64][32][4096]
#define U_BASE  17000000u   // f16 weights (as _Float16 offsets):
// [0,1M) Whh_f | [1M,2M) Whh_b | [2M,10.49M) WDEC [4096][2048]
// [10.49M,11.53M) Wih_f | [11.53M,12.58M) Wih_b | [12.58M,14.68M) WFEED [4096][512]
// [14.68M,15.73M) WA [1024][1024]
#define U_WIHF  10485760u
#define U_WIHB  11534336u
#define U_WFEED 12582912u
#define U_WA    14680064u
#define U_TOTAL 15728640u

typedef float f32x4 __attribute__((ext_vector_type(4)));
typedef _Float16 f16x8 __attribute__((ext_vector_type(8)));
typedef _Float16 f16x4 __attribute__((ext_vector_type(4)));

__device__ __forceinline__ float sigm_(float x){ return 1.0f/(1.0f + expf(-x)); }

__device__ __forceinline__ unsigned int fkey_(float f){
  unsigned int u = __float_as_uint(f);
  return (u & 0x80000000u) ? ~u : (u | 0x80000000u);
}

// XOR swizzle for f16 tiles with 64B rows (32 halves)
__device__ __forceinline__ int swz_(int row, int kb){
  return (row*64 + kb) ^ ((row & 7) << 4);
}

// ---------------- init ----------------
__global__ __launch_bounds__(256) void k_init(float* __restrict__ ws){
  int i = blockIdx.x*256 + threadIdx.x;
  if (i < 65536) ws[i] = 0.0f;   // both c-parity buffers
  if (i < 2048) ((unsigned long long*)(ws + O_PACK))[i] = 0ull;
}

// ---------------- weight f16 conversion (once) ----------------
__global__ __launch_bounds__(256) void k_cvtW(
    const float* __restrict__ Whh_f, const float* __restrict__ Whh_b,
    const float* __restrict__ Wih_d, const float* __restrict__ Whh_d,
    const float* __restrict__ Wih_f, const float* __restrict__ Wih_b,
    const float* __restrict__ Wa,
    _Float16* __restrict__ dst)
{
  int g = blockIdx.x*256 + threadIdx.x;
  unsigned idx = (unsigned)g*4u;
  if (idx >= U_TOTAL) return;
  f32x4 v;
  if (idx < 1048576u){
    v = *(const f32x4*)(Whh_f + idx);
  } else if (idx < 2097152u){
    v = *(const f32x4*)(Whh_b + (idx - 1048576u));
  } else if (idx < U_WIHF){
    unsigned j = idx - 2097152u;
    unsigned row = j >> 11, col = j & 2047u;
    const float* src = (col < 1024u) ? (Wih_d + (size_t)row*1536 + col)
                                     : (Whh_d + (size_t)row*1024 + (col - 1024u));
    v = *(const f32x4*)src;
  } else if (idx < U_WIHB){
    v = *(const f32x4*)(Wih_f + (idx - U_WIHF));
  } else if (idx < U_WFEED){
    v = *(const f32x4*)(Wih_b + (idx - U_WIHB));
  } else if (idx < U_WA){
    unsigned j = idx - U_WFEED;
    unsigned row = j >> 9, col = j & 511u;
    v = *(const f32x4*)(Wih_d + (size_t)row*1536 + 1024 + col);
  } else {
    v = *(const f32x4*)(Wa + (idx - U_WA));
  }
  f16x4 h;
  #pragma unroll
  for (int c = 0; c < 4; ++c) h[c] = (_Float16)v[c];
  *(f16x4*)(dst + idx) = h;
}

// ---------------- Wout f16 conversion (once, only if ws big enough) --------
__global__ __launch_bounds__(256) void k_cvtWout(
    const float* __restrict__ Wout, _Float16* __restrict__ W1)
{
  size_t i = ((size_t)blockIdx.x*256 + threadIdx.x)*8;
  f32x4 x0 = *(const f32x4*)(Wout + i);
  f32x4 x1 = *(const f32x4*)(Wout + i + 4);
  f16x4 h0, h1;
  #pragma unroll
  for (int c = 0; c < 4; ++c){ h0[c] = (_Float16)x0[c]; h1[c] = (_Float16)x1[c]; }
  *(f16x4*)(W1 + i)   = h0;
  *(f16x4*)(W1 + i+4) = h1;
}

// ---- projection GEMM via MFMA: C[M,N] = gather/plain A(fp32) * Wh(f16)^T + biases ----
// MODE 0: plain A rows (stride K).  MODE 1: enc gather.  MODE 2: feed gather (t==0 zero).
// Tile 128x128, BK=32, A split hi/lo*2048 in-kernel (2-product).
template<int MODE>
__global__ __launch_bounds__(256) void k_proj(
    const float* __restrict__ Asrc, const int* __restrict__ chunk, int K,
    const _Float16* __restrict__ Wh,
    const float* __restrict__ bias0, const float* __restrict__ bias1,
    float* __restrict__ C, int ldC)
{
  __shared__ char lds[49152];  // 2 bufs x (A1 8K | A2 8K | W 8K)
  int tid = threadIdx.x;
  int n0 = blockIdx.x*128, m0 = blockIdx.y*128;
  int lane = tid & 63, wave = tid >> 6;
  int wm = wave >> 1, wn = wave & 1;
  int lr = lane & 15, lg = lane >> 4;

  int s0 = tid*2, s1 = tid*2 + 1;
  int ar0 = s0 >> 2, as0 = s0 & 3;
  int ar1 = s1 >> 2, as1 = s1 & 3;

  const float* arp0; const float* arp1;
  {
    int m = m0 + ar0;
    if (MODE == 0){ arp0 = Asrc + (size_t)m*K + as0*8; }
    else if (MODE == 1){ int s = m >> 5, b = m & 31; arp0 = Asrc + (size_t)chunk[b*SS + s]*EE + as0*8; }
    else { int tt = m >> 5, b = m & 31; arp0 = tt ? (Asrc + (size_t)chunk[b*TT + (tt-1)]*EE + as0*8) : nullptr; }
    m = m0 + ar1;
    if (MODE == 0){ arp1 = Asrc + (size_t)m*K + as1*8; }
    else if (MODE == 1){ int s = m >> 5, b = m & 31; arp1 = Asrc + (size_t)chunk[b*SS + s]*EE + as1*8; }
    else { int tt = m >> 5, b = m & 31; arp1 = tt ? (Asrc + (size_t)chunk[b*TT + (tt-1)]*EE + as1*8) : nullptr; }
  }
  const _Float16* wp0 = Wh + (size_t)(n0 + ar0)*K + as0*8;
  const _Float16* wp1 = Wh + (size_t)(n0 + ar1)*K + as1*8;

  f32x4 accH[4][4], accM[4][4];
  #pragma unroll
  for (int i = 0; i < 4; ++i)
    #pragma unroll
    for (int j = 0; j < 4; ++j){
      f32x4 z; z[0]=z[1]=z[2]=z[3]=0.f;
      accH[i][j] = z; accM[i][j] = z;
    }

  f32x4 zz; zz[0]=zz[1]=zz[2]=zz[3]=0.f;
  f32x4 a0a, a0b, a1a, a1b;
  uint4 rw0, rw1;
  a0a = arp0 ? *(const f32x4*)(arp0)     : zz;
  a0b = arp0 ? *(const f32x4*)(arp0 + 4) : zz;
  a1a = arp1 ? *(const f32x4*)(arp1)     : zz;
  a1b = arp1 ? *(const f32x4*)(arp1 + 4) : zz;
  rw0 = *(const uint4*)wp0;
  rw1 = *(const uint4*)wp1;

  int kiters = K >> 5;
  for (int kt = 0; kt < kiters; ++kt){
    char* base = lds + (kt & 1)*24576;
    char* A1t = base, *A2t = base + 8192, *Wt = base + 16384;
    f16x8 h0, l0, h1, l1;
    #pragma unroll
    for (int c = 0; c < 4; ++c){
      float x = a0a[c]; _Float16 hh = (_Float16)x;
      h0[c] = hh; l0[c] = (_Float16)((x - (float)hh)*2048.0f);
      x = a0b[c]; hh = (_Float16)x;
      h0[4+c] = hh; l0[4+c] = (_Float16)((x - (float)hh)*2048.0f);
      x = a1a[c]; hh = (_Float16)x;
      h1[c] = hh; l1[c] = (_Float16)((x - (float)hh)*2048.0f);
      x = a1b[c]; hh = (_Float16)x;
      h1[4+c] = hh; l1[4+c] = (_Float16)((x - (float)hh)*2048.0f);
    }
    *(f16x8*)(A1t + swz_(ar0, as0*16)) = h0;
    *(f16x8*)(A2t + swz_(ar0, as0*16)) = l0;
    *(f16x8*)(A1t + swz_(ar1, as1*16)) = h1;
    *(f16x8*)(A2t + swz_(ar1, as1*16)) = l1;
    *(uint4*)(Wt + swz_(ar0, as0*16)) = rw0;
    *(uint4*)(Wt + swz_(ar1, as1*16)) = rw1;
    __syncthreads();
    if (kt < kiters-1){
      int ko = (kt+1)*32;
      a0a = arp0 ? *(const f32x4*)(arp0 + ko)     : zz;
      a0b = arp0 ? *(const f32x4*)(arp0 + ko + 4) : zz;
      a1a = arp1 ? *(const f32x4*)(arp1 + ko)     : zz;
      a1b = arp1 ? *(const f32x4*)(arp1 + ko + 4) : zz;
      rw0 = *(const uint4*)(wp0 + ko);
      rw1 = *(const uint4*)(wp1 + ko);
    }
    f16x8 wf[4];
    #pragma unroll
    for (int nf = 0; nf < 4; ++nf)
      wf[nf] = *(const f16x8*)(Wt + swz_(wn*64 + nf*16 + lr, lg*16));
    #pragma unroll
    for (int mf = 0; mf < 4; ++mf){
      int ad = swz_(wm*64 + mf*16 + lr, lg*16);
      f16x8 a1f = *(const f16x8*)(A1t + ad);
      f16x8 a2f = *(const f16x8*)(A2t + ad);
      #pragma unroll
      for (int nf = 0; nf < 4; ++nf){
        accH[mf][nf] = __builtin_amdgcn_mfma_f32_16x16x32_f16(a1f, wf[nf], accH[mf][nf], 0, 0, 0);
        accM[mf][nf] = __builtin_amdgcn_mfma_f32_16x16x32_f16(a2f, wf[nf], accM[mf][nf], 0, 0, 0);
      }
    }
    __syncthreads();
  }

  const float rs = 1.0f/2048.0f;
  float bb[4];
  #pragma unroll
  for (int nf = 0; nf < 4; ++nf){
    int n = n0 + wn*64 + nf*16 + lr;
    bb[nf] = bias0[n] + (bias1 ? bias1[n] : 0.0f);
  }
  #pragma unroll
  for (int mf = 0; mf < 4; ++mf){
    #pragma unroll
    for (int r = 0; r < 4; ++r){
      int m = m0 + wm*64 + mf*16 + lg*4 + r;
      #pragma unroll
      for (int nf = 0; nf < 4; ++nf){
        int n = n0 + wn*64 + nf*16 + lr;
        C[(size_t)m*ldC + n] = accH[mf][nf][r] + accM[mf][nf][r]*rs + bb[nf];
      }
    }
  }
}

// ---------------- fused encoder step (f16 Whh) ----------------
// grid (16 sub, 4 kp, 2 dir) x 256.  Partials parity: read (t&1? PDEC:PENC), write other.
__global__ __launch_bounds__(256) void k_enc_step(
    const _Float16* __restrict__ wenc,
    float* __restrict__ ws, const float* __restrict__ oscr, int t)
{
  __shared__ float hl[128*36];
  __shared__ float Wt[32*132];
  int sub = blockIdx.x, kp = blockIdx.y, dir = blockIdx.z;
  int tid = threadIdx.x;
  int s = dir ? (63 - t) : t;
  int p = t & 1;
  const float* gx  = oscr + (dir ? S_GXB : S_GXF);
  const float* prd = ws + (p ? O_PDEC : O_PENC) + dir*262144u;
  const float* cin = ws + O_C0 + p*32768u + dir*16384u;
  float* cout = ws + O_C0 + (p^1)*32768u + dir*16384u;

  {
    int ug = tid & 31, bg = tid >> 5;
    int ul0 = ug*4;
    int u0 = kp*128 + ul0;
    #pragma unroll
    for (int j = 0; j < 4; ++j){
      int b = bg*4 + j;
      size_t gbase = (size_t)(s*32 + b)*2048u;
      f32x4 g0 = *(const f32x4*)&gx[gbase + u0];
      f32x4 g1 = *(const f32x4*)&gx[gbase + 512 + u0];
      f32x4 g2 = *(const f32x4*)&gx[gbase + 1024 + u0];
      f32x4 g3 = *(const f32x4*)&gx[gbase + 1536 + u0];
      if (t > 0){
        #pragma unroll
        for (int kq = 0; kq < 4; ++kq){
          const float* pp = prd + kq*65536u + (size_t)b*2048u;
          g0 += *(const f32x4*)&pp[u0];
          g1 += *(const f32x4*)&pp[512 + u0];
          g2 += *(const f32x4*)&pp[1024 + u0];
          g3 += *(const f32x4*)&pp[1536 + u0];
        }
      }
      f32x4 c = *(const f32x4*)&cin[b*512 + u0];
      f32x4 cn, hn;
      #pragma unroll
      for (int e = 0; e < 4; ++e){
        float cc = sigm_(g1[e])*c[e] + sigm_(g0[e])*tanhf(g2[e]);
        float hh = sigm_(g3[e])*tanhf(cc);
        cn[e] = cc; hn[e] = hh;
        hl[(ul0+e)*36 + b] = hh;
      }
      if (sub == 0){
        *(f32x4*)&cout[b*512 + u0] = cn;
        *(f32x4*)&ws[O_ALLH + (size_t)(b*64 + s)*1024u + dir*512 + u0] = hn;
      }
    }
  }
  __syncthreads();
  if (t == 63) return;

  const _Float16* W = wenc + dir*1048576u;
  float* P = ws + (p ? O_PENC : O_PDEC) + dir*262144u + kp*65536u;
  int rg2 = tid & 31, bg2 = tid >> 5;
  int wrow = tid & 127, whalf = tid >> 7;
  float acc[4][4] = {};
  for (int kt = 0; kt < 4; ++kt){
    #pragma unroll
    for (int i = 0; i < 4; ++i){
      int chunk = whalf*4 + i;
      int grow = sub*128 + wrow;
      f16x4 v = *(const f16x4*)&W[(size_t)grow*512 + kp*128 + kt*32 + chunk*4];
      Wt[(chunk*4+0)*132 + wrow] = (float)v[0];
      Wt[(chunk*4+1)*132 + wrow] = (float)v[1];
      Wt[(chunk*4+2)*132 + wrow] = (float)v[2];
      Wt[(chunk*4+3)*132 + wrow] = (float)v[3];
    }
    __syncthreads();
    #pragma unroll 8
    for (int kk = 0; kk < 32; ++kk){
      f32x4 wv = *(const f32x4*)&Wt[kk*132 + rg2*4];
      f32x4 hv = *(const f32x4*)&hl[(kt*32+kk)*36 + bg2*4];
      #pragma unroll
      for (int i = 0; i < 4; ++i)
        #pragma unroll
        for (int j = 0; j < 4; ++j)
          acc[i][j] = fmaf(wv[i], hv[j], acc[i][j]);
    }
    __syncthreads();
  }
  #pragma unroll
  for (int j = 0; j < 4; ++j){
    int b = bg2*4 + j;
    f32x4 v; v[0]=acc[0][j]; v[1]=acc[1][j]; v[2]=acc[2][j]; v[3]=acc[3][j];
    *(f32x4*)&P[(size_t)b*2048u + sub*128 + rg2*4] = v;
  }
}

// ---------------- decoder state init ----------------
__global__ __launch_bounds__(256) void k_concat(float* __restrict__ ws){
  int i = blockIdx.x*256 + threadIdx.x;   // 0..65535
  int which = i >> 15;
  int idx = i & 32767;
  int b = idx >> 10, u = idx & 1023;
  int dir = (u >= 512);
  int uu = u & 511;
  float v;
  if (which == 0){
    int s = dir ? 0 : 63;
    v = ws[O_ALLH + (size_t)(b*64 + s)*1024u + u];
  } else {
    v = ws[O_C0 + dir*16384u + b*512 + uu];
  }
  ws[(which ? O_CD : O_HD) + b*1024 + u] = v;
}

// ---------------- decoder gate GEMM via MFMA (2-product split-A, f16 W) ----
// grid (64 nb, 4 kp) x 256 (4 waves). K-slice 512, BN=64.
__global__ __launch_bounds__(256) void k_dec_gemm(
    const _Float16* __restrict__ wdec, float* __restrict__ ws)
{
  __shared__ char lds[16384];   // 2 bufs x (A1 2K | A2 2K | W 4K)
  int nb = blockIdx.x, kp = blockIdx.y;
  int tid = threadIdx.x;
  int lane = tid & 63, w = tid >> 6;
  int lr = lane & 15, lg = lane >> 4;
  const _Float16* A1g = (const _Float16*)(ws + O_DA1);
  const _Float16* A2g = (const _Float16*)(ws + O_DA2);

  int aslot = tid & 127;
  int isA2  = tid >> 7;
  int arow = aslot >> 2, aseg = aslot & 3;
  int wrow = tid >> 2, wseg = tid & 3;
  const _Float16* asrc = (isA2 ? A2g : A1g) + (size_t)arow*2048u + kp*512 + aseg*8;
  const _Float16* wsrc = wdec + (size_t)(nb*64 + wrow)*2048u + kp*512 + wseg*8;

  f32x4 accH[2], accM[2];
  #pragma unroll
  for (int i = 0; i < 2; ++i){ f32x4 z; z[0]=z[1]=z[2]=z[3]=0.f; accH[i]=z; accM[i]=z; }

  uint4 rA = *(const uint4*)(asrc);
  uint4 rW = *(const uint4*)(wsrc);

  for (int kt = 0; kt < 16; ++kt){
    int cur = kt & 1;
    char* base = lds + cur*8192;
    *(uint4*)(base + (isA2 ? 2048 : 0) + swz_(arow, aseg*16)) = rA;
    *(uint4*)(base + 4096 + swz_(wrow, wseg*16)) = rW;
    __syncthreads();
    if (kt < 15){
      rA = *(const uint4*)(asrc + (kt+1)*32);
      rW = *(const uint4*)(wsrc + (kt+1)*32);
    }
    char* A1t = base, *A2t = base + 2048, *Wt = base + 4096;
    f16x8 wf = *(const f16x8*)(Wt + swz_(w*16 + lr, lg*16));
    #pragma unroll
    for (int mf = 0; mf < 2; ++mf){
      f16x8 a1 = *(const f16x8*)(A1t + swz_(mf*16 + lr, lg*16));
      f16x8 a2 = *(const f16x8*)(A2t + swz_(mf*16 + lr, lg*16));
      accH[mf] = __builtin_amdgcn_mfma_f32_16x16x32_f16(a1, wf, accH[mf], 0, 0, 0);
      accM[mf] = __builtin_amdgcn_mfma_f32_16x16x32_f16(a2, wf, accM[mf], 0, 0, 0);
    }
    __syncthreads();
  }
  const float rs = 1.0f/2048.0f;
  float* P = ws + O_PDEC + (size_t)kp*131072u;
  #pragma unroll
  for (int mf = 0; mf < 2; ++mf)
    #pragma unroll
    for (int r = 0; r < 4; ++r){
      int b = mf*16 + lg*4 + r;
      int n = nb*64 + w*16 + lr;
      P[(size_t)b*4096u + n] = accH[mf][r] + accM[mf][r]*rs;
    }
}

// ---------------- attention step (fuses pointwise of step t-1), 32 blocks ----------
__global__ __launch_bounds__(256) void k_attn(float* __restrict__ ws,
                                              const float* __restrict__ oscr, int t){
  __shared__ float hlq[1024];
  __shared__ float part[64][5];
  __shared__ float sc[64];
  __shared__ float atn[64];
  __shared__ float dsh;
  int b = blockIdx.x, tid = threadIdx.x;
  float* hd = ws + O_HD;
  float* cd = ws + O_CD;
  _Float16* DA1 = (_Float16*)(ws + O_DA1);
  _Float16* DA2 = (_Float16*)(ws + O_DA2);
  if (t > 0){
    const float* gfd = oscr + S_GFEED + (size_t)((t-1)*32 + b)*4096u;
    const float* pd = ws + O_PDEC;
    for (int u = tid; u < 1024; u += 256){
      float g0 = gfd[u], g1 = gfd[1024+u], g2 = gfd[2048+u], g3 = gfd[3072+u];
      #pragma unroll
      for (int kp = 0; kp < 4; ++kp){
        const float* p = pd + (size_t)kp*131072u + (size_t)b*4096u;
        g0 += p[u]; g1 += p[1024+u]; g2 += p[2048+u]; g3 += p[3072+u];
      }
      float c = cd[b*1024 + u];
      c = sigm_(g1)*c + sigm_(g0)*tanhf(g2);
      float h = sigm_(g3)*tanhf(c);
      cd[b*1024+u] = c; hd[b*1024+u] = h; hlq[u] = h;
      ws[O_HDEC + (size_t)(b*64 + (t-1))*1024u + u] = h;
      _Float16 hi = (_Float16)h;
      DA1[(size_t)b*2048u + 1024 + u] = hi;
      DA2[(size_t)b*2048u + 1024 + u] = (_Float16)((h - (float)hi)*2048.0f);
    }
  } else {
    for (int u = tid; u < 1024; u += 256){
      float h = hd[b*1024 + u];
      hlq[u] = h;
      _Float16 hi = (_Float16)h;
      DA1[(size_t)b*2048u + 1024 + u] = hi;
      DA2[(size_t)b*2048u + 1024 + u] = (_Float16)((h - (float)hi)*2048.0f);
    }
  }
  __syncthreads();
  {
    int s = tid >> 2, p = tid & 3;
    const float* Ar = ws + O_AATT + (size_t)(b*64 + s)*1024u + p*256;
    const float* hp = &hlq[p*256];
    float sum = 0.f;
    #pragma unroll 8
    for (int k4 = 0; k4 < 64; ++k4){
      float4 a = *(const float4*)&Ar[k4*4];
      float4 h4 = *(const float4*)&hp[k4*4];
      sum = fmaf(a.x,h4.x, fmaf(a.y,h4.y, fmaf(a.z,h4.z, fmaf(a.w,h4.w, sum))));
    }
    part[s][p] = sum;
  }
  __syncthreads();
  if (tid < 64) sc[tid] = part[tid][0] + part[tid][1] + part[tid][2] + part[tid][3];
  __syncthreads();
  if (tid < 64){
    float m = sc[0];
    #pragma unroll
    for (int i = 1; i < 64; ++i) m = fmaxf(m, sc[i]);
    atn[tid] = expf(sc[tid] - m);
  }
  __syncthreads();
  if (tid == 0){
    float d = 0.f;
    #pragma unroll
    for (int i = 0; i < 64; ++i) d += atn[i];
    dsh = 1.0f/d;
  }
  __syncthreads();
  {
    float rd = dsh;
    float ax=0.f, ay=0.f, az=0.f, aw=0.f;
    const float* ah = ws + O_ALLH + (size_t)(b*64)*1024u + tid*4;
    for (int s2 = 0; s2 < 64; ++s2){
      float a = atn[s2];
      float4 v = *(const float4*)&ah[(size_t)s2*1024u];
      ax = fmaf(a, v.x, ax); ay = fmaf(a, v.y, ay);
      az = fmaf(a, v.z, az); aw = fmaf(a, v.w, aw);
    }
    float o[4] = {ax*rd, ay*rd, az*rd, aw*rd};
    #pragma unroll
    for (int j = 0; j < 4; ++j){
      int u = tid*4 + j;
      _Float16 hi = (_Float16)o[j];
      DA1[(size_t)b*2048u + u] = hi;
      DA2[(size_t)b*2048u + u] = (_Float16)((o[j] - (float)hi)*2048.0f);
    }
  }
}

// ---------------- finalize: pw_last (t=63) + cvtA, one launch, 128 blocks ----
__global__ __launch_bounds__(256) void k_fin(float* __restrict__ ws,
                                             const float* __restrict__ oscr){
  int bid = blockIdx.x, tid = threadIdx.x;
  if ((bid & 3) == 3){
    int b = bid >> 2;
    const float* gfd = oscr + S_GFEED + (size_t)(63*32 + b)*4096u;
    const float* pd = ws + O_PDEC;
    for (int q = 0; q < 4; ++q){
      int u = q*256 + tid;
      float g0 = gfd[u], g1 = gfd[1024+u], g2 = gfd[2048+u], g3 = gfd[3072+u];
      #pragma unroll
      for (int kp = 0; kp < 4; ++kp){
        const float* p = pd + (size_t)kp*131072u + (size_t)b*4096u;
        g0 += p[u]; g1 += p[1024+u]; g2 += p[2048+u]; g3 += p[3072+u];
      }
      float c = ws[O_CD + b*1024 + u];
      c = sigm_(g1)*c + sigm_(g0)*tanhf(g2);
      float h = sigm_(g3)*tanhf(c);
      ws[O_HDEC + (size_t)(b*64 + 63)*1024u + u] = h;
    }
  }
  __syncthreads();
  const float* src = ws + O_HDEC;
  _Float16* A1 = (_Float16*)(ws + O_ALLH);
  _Float16* A2 = (_Float16*)(ws + O_AATT);
  for (int rep = 0; rep < 8; ++rep){
    int i = bid*16384 + (rep*256 + tid)*8;
    f32x4 x0 = *(const f32x4*)&src[i];
    f32x4 x1 = *(const f32x4*)&src[i+4];
    f16x4 h0, h1, l0, l1;
    #pragma unroll
    for (int c = 0; c < 4; ++c){
      _Float16 a = (_Float16)x0[c];
      h0[c] = a; l0[c] = (_Float16)((x0[c] - (float)a)*2048.0f);
      _Float16 bq = (_Float16)x1[c];
      h1[c] = bq; l1[c] = (_Float16)((x1[c] - (float)bq)*2048.0f);
    }
    *(f16x4*)&A1[i]   = h0;
    *(f16x4*)&A1[i+4] = h1;
    *(f16x4*)&A2[i]   = l0;
    *(f16x4*)&A2[i+4] = l1;
  }
}

// ---------------- logits (primary): A-direct 2-product f16 MFMA, W-only LDS ---
// grid (16 m, 250 n) x 256 (4 waves 2m x 2n). BM=BN=128, BK=32, W dbuf LDS 16KB.
__global__ __launch_bounds__(256) void k_logits(
    const _Float16* __restrict__ A1, const _Float16* __restrict__ A2,
    const _Float16* __restrict__ W1, const float* __restrict__ bout,
    float* __restrict__ out, unsigned long long* __restrict__ pk)
{
  __shared__ char lds[16384];  // 2 bufs x (W 8K)
  int tid = threadIdx.x;
  int n0 = blockIdx.y*128, m0 = blockIdx.x*128;
  int lane = tid & 63, wave = tid >> 6;
  int wm = wave >> 1, wn = wave & 1;
  int lr = lane & 15, lg = lane >> 4;

  int s0 = tid*2, s1 = tid*2 + 1;
  int wr0 = s0 >> 2, wg0 = s0 & 3;
  int wr1 = s1 >> 2, wg1 = s1 & 3;
  const _Float16* wp0 = W1 + (size_t)(n0 + wr0)*1024u + wg0*8;
  const _Float16* wp1 = W1 + (size_t)(n0 + wr1)*1024u + wg1*8;

  // A fragment base: wave wm owns rows [wm*64, wm*64+64), lane lr picks row, lg picks k-octet
  const _Float16* a1b = A1 + (size_t)(m0 + wm*64 + lr)*1024u + lg*8;
  const _Float16* a2b = A2 + (size_t)(m0 + wm*64 + lr)*1024u + lg*8;

  f32x4 accH[4][4], accM[4][4];
  #pragma unroll
  for (int i = 0; i < 4; ++i)
    #pragma unroll
    for (int j = 0; j < 4; ++j){
      f32x4 z; z[0]=z[1]=z[2]=z[3]=0.f;
      accH[i][j] = z; accM[i][j] = z;
    }

  uint4 rw0 = *(const uint4*)wp0;
  uint4 rw1 = *(const uint4*)wp1;
  f16x8 a1f[4], a2f[4];
  #pragma unroll
  for (int mf = 0; mf < 4; ++mf){
    a1f[mf] = *(const f16x8*)(a1b + mf*16*1024);
    a2f[mf] = *(const f16x8*)(a2b + mf*16*1024);
  }

  for (int kt = 0; kt < 32; ++kt){
    char* Wt = lds + (kt & 1)*8192;
    *(uint4*)(Wt + swz_(wr0, wg0*16)) = rw0;
    *(uint4*)(Wt + swz_(wr1, wg1*16)) = rw1;
    __syncthreads();
    if (kt < 31){
      int ko = (kt+1)*32;
      rw0 = *(const uint4*)(wp0 + ko);
      rw1 = *(const uint4*)(wp1 + ko);
    }
    f16x8 wf[4];
    #pragma unroll
    for (int nf = 0; nf < 4; ++nf)
      wf[nf] = *(const f16x8*)(Wt + swz_(wn*64 + nf*16 + lr, lg*16));
    f16x8 c1[4], c2[4];
    #pragma unroll
    for (int mf = 0; mf < 4; ++mf){ c1[mf] = a1f[mf]; c2[mf] = a2f[mf]; }
    if (kt < 31){
      int ko = (kt+1)*32;
      #pragma unroll
      for (int mf = 0; mf < 4; ++mf){
        a1f[mf] = *(const f16x8*)(a1b + mf*16*1024 + ko);
        a2f[mf] = *(const f16x8*)(a2b + mf*16*1024 + ko);
      }
    }
    #pragma unroll
    for (int mf = 0; mf < 4; ++mf)
      #pragma unroll
      for (int nf = 0; nf < 4; ++nf){
        accH[mf][nf] = __builtin_amdgcn_mfma_f32_16x16x32_f16(c1[mf], wf[nf], accH[mf][nf], 0, 0, 0);
        accM[mf][nf] = __builtin_amdgcn_mfma_f32_16x16x32_f16(c2[mf], wf[nf], accM[mf][nf], 0, 0, 0);
      }
    __syncthreads();
  }

  const float rs = 1.0f/2048.0f;
  float bb[4];
  #pragma unroll
  for (int nf = 0; nf < 4; ++nf) bb[nf] = bout[n0 + wn*64 + nf*16 + lr];
  #pragma unroll
  for (int mf = 0; mf < 4; ++mf){
    #pragma unroll
    for (int r = 0; r < 4; ++r){
      int m = m0 + wm*64 + mf*16 + lg*4 + r;
      unsigned long long bk = 0ull;
      #pragma unroll
      for (int nf = 0; nf < 4; ++nf){
        int n = n0 + wn*64 + nf*16 + lr;
        float val = accH[mf][nf][r] + accM[mf][nf][r]*rs + bb[nf];
        __builtin_nontemporal_store(val, &out[(size_t)m*VV + n]);
        unsigned long long p = ((unsigned long long)fkey_(val) << 32) | (unsigned int)(~(unsigned int)n);
        if (p > bk) bk = p;
      }
      #pragma unroll
      for (int off = 1; off < 16; off <<= 1){
        unsigned long long o = __shfl_xor(bk, off, 64);
        if (o > bk) bk = o;
      }
      if (lr == 0) atomicMax(&pk[m], bk);
    }
  }
}

// ---------------- logits fallback (small ws): in-kernel split, 3 products ----
__global__ __launch_bounds__(512) void k_logits_fb(
    const _Float16* __restrict__ A1, const _Float16* __restrict__ A2,
    const float* __restrict__ Wout, const float* __restrict__ bout,
    float* __restrict__ out, unsigned long long* __restrict__ pk)
{
  __shared__ char lds[49152];
  char* A1t = lds;
  char* A2t = lds + 8192;
  char* W1t = lds + 16384;
  char* W2t = lds + 32768;
  int tid = threadIdx.x;
  int n0 = blockIdx.x*256;
  int lane = tid & 63, wave = tid >> 6;
  int wm = wave >> 2, wn = wave & 3;
  int lr = lane & 15, lg = lane >> 4;

  int arow = tid >> 2, aseg = tid & 3;
  int wrow = tid >> 1, wseg = tid & 1;
  const float* wp = Wout + (size_t)(n0 + wrow)*1024u + wseg*16;

  float bb[4];
  #pragma unroll
  for (int nf = 0; nf < 4; ++nf) bb[nf] = bout[n0 + wn*64 + nf*16 + lr];
  const float rs = 1.0f/2048.0f;

  for (int mi = 0; mi < 4; ++mi){
    int m0 = (blockIdx.y*4 + mi)*128;
    const _Float16* a1p = A1 + (size_t)(m0 + arow)*1024u + aseg*8;
    const _Float16* a2p = A2 + (size_t)(m0 + arow)*1024u + aseg*8;

    f32x4 accH[4][4], accM[4][4];
    #pragma unroll
    for (int i = 0; i < 4; ++i)
      #pragma unroll
      for (int j = 0; j < 4; ++j){
        f32x4 z; z[0]=z[1]=z[2]=z[3]=0.f;
        accH[i][j] = z; accM[i][j] = z;
      }

    for (int k0 = 0; k0 < 1024; k0 += 32){
      uint4 av1 = *(const uint4*)(a1p + k0);
      uint4 av2 = *(const uint4*)(a2p + k0);
      f32x4 wv[4];
      #pragma unroll
      for (int i = 0; i < 4; ++i) wv[i] = *(const f32x4*)(wp + k0 + i*4);
      __syncthreads();
      *(uint4*)(A1t + swz_(arow, aseg*16)) = av1;
      *(uint4*)(A2t + swz_(arow, aseg*16)) = av2;
      f16x8 hi[2], lo[2];
      #pragma unroll
      for (int i = 0; i < 2; ++i)
        #pragma unroll
        for (int c = 0; c < 8; ++c){
          float x = wv[i*2 + (c>>2)][c&3];
          _Float16 h = (_Float16)x;
          hi[i][c] = h;
          lo[i][c] = (_Float16)((x - (float)h)*2048.0f);
        }
      *(f16x8*)(W1t + swz_(wrow, wseg*32 +  0)) = hi[0];
      *(f16x8*)(W1t + swz_(wrow, wseg*32 + 16)) = hi[1];
      *(f16x8*)(W2t + swz_(wrow, wseg*32 +  0)) = lo[0];
      *(f16x8*)(W2t + swz_(wrow, wseg*32 + 16)) = lo[1];
      __syncthreads();
      f16x8 w1f[4], w2f[4];
      #pragma unroll
      for (int nf = 0; nf < 4; ++nf){
        int ad = swz_(wn*64 + nf*16 + lr, lg*16);
        w1f[nf] = *(const f16x8*)(W1t + ad);
        w2f[nf] = *(const f16x8*)(W2t + ad);
      }
      #pragma unroll
      for (int mf = 0; mf < 4; ++mf){
        int ad = swz_(wm*64 + mf*16 + lr, lg*16);
        f16x8 a1f = *(const f16x8*)(A1t + ad);
        f16x8 a2f = *(const f16x8*)(A2t + ad);
        #pragma unroll
        for (int nf = 0; nf < 4; ++nf){
          accH[mf][nf] = __builtin_amdgcn_mfma_f32_16x16x32_f16(a1f, w1f[nf], accH[mf][nf], 0, 0, 0);
          accM[mf][nf] = __builtin_amdgcn_mfma_f32_16x16x32_f16(a1f, w2f[nf], accM[mf][nf], 0, 0, 0);
          accM[mf][nf] = __builtin_amdgcn_mfma_f32_16x16x32_f16(a2f, w1f[nf], accM[mf][nf], 0, 0, 0);
        }
      }
    }

    #pragma unroll
    for (int mf = 0; mf < 4; ++mf){
      #pragma unroll
      for (int r = 0; r < 4; ++r){
        int m = m0 + wm*64 + mf*16 + lg*4 + r;
        unsigned long long bk = 0ull;
        #pragma unroll
        for (int nf = 0; nf < 4; ++nf){
          int n = n0 + wn*64 + nf*16 + lr;
          float val = accH[mf][nf][r] + accM[mf][nf][r]*rs + bb[nf];
          __builtin_nontemporal_store(val, &out[(size_t)m*VV + n]);
          unsigned long long p = ((unsigned long long)fkey_(val) << 32) | (unsigned int)(~(unsigned int)n);
          if (p > bk) bk = p;
        }
        #pragma unroll
        for (int off = 1; off < 16; off <<= 1){
          unsigned long long o = __shfl_xor(bk, off, 64);
          if (o > bk) bk = o;
        }
        if (lr == 0) atomicMax(&pk[m], bk);
      }
    }
  }
}

__global__ __launch_bounds__(256) void k_argmax(
    const unsigned long long* __restrict__ pk, float* __restrict__ out)
{
  int i = blockIdx.x*256 + threadIdx.x;
  if (i < 2048){
    unsigned int low = (unsigned int)(pk[i] & 0xFFFFFFFFull);
    unsigned int col = ~low;
    out[(size_t)BB*TT*VV + i] = (float)col;
  }
}

extern "C" void kernel_launch(void* const* d_in, const int* in_sizes, int n_in,
                              void* d_out, int out_size, void* d_ws, size_t ws_size,
                              hipStream_t stream)
{
  const int*   input_chunk  = (const int*)d_in[0];
  const int*   target_chunk = (const int*)d_in[1];
  const float* enc_emb = (const float*)d_in[2];
  const float* dec_emb = (const float*)d_in[3];
  const float* Wih_f = (const float*)d_in[4];
  const float* Whh_f = (const float*)d_in[5];
  const float* bih_f = (const float*)d_in[6];
  const float* bhh_f = (const float*)d_in[7];
  const float* Wih_b = (const float*)d_in[8];
  const float* Whh_b = (const float*)d_in[9];
  const float* bih_b = (const float*)d_in[10];
  const float* bhh_b = (const float*)d_in[11];
  const float* Wih_d = (const float*)d_in[12];
  const float* Whh_d = (const float*)d_in[13];
  const float* bih_d = (const float*)d_in[14];
  const float* bhh_d = (const float*)d_in[15];
  const float* Wa   = (const float*)d_in[16];
  const float* ba   = (const float*)d_in[17];
  const float* Wout = (const float*)d_in[18];
  const float* bout = (const float*)d_in[19];
  float* ws = (float*)d_ws;
  float* out = (float*)d_out;
  float* oscr = (float*)d_out;
  _Float16* wf16 = (_Float16*)(oscr + U_BASE);
  bool bigws = (ws_size >= WS_NEED);

  k_init<<<256, 256, 0, stream>>>(ws);
  k_cvtW<<<15360, 256, 0, stream>>>(Whh_f, Whh_b, Wih_d, Whh_d, Wih_f, Wih_b, Wa, wf16);
  if (bigws)
    k_cvtWout<<<16000, 256, 0, stream>>>(Wout, (_Float16*)(ws + O_W1));

  // batched input projections via MFMA (biases folded) into d_out scratch
  k_proj<1><<<dim3(16,16), 256, 0, stream>>>(enc_emb, input_chunk, 512, wf16 + U_WIHF, bih_f, bhh_f, oscr + S_GXF, 2048);
  k_proj<1><<<dim3(16,16), 256, 0, stream>>>(enc_emb, input_chunk, 512, wf16 + U_WIHB, bih_b, bhh_b, oscr + S_GXB, 2048);
  k_proj<2><<<dim3(32,16), 256, 0, stream>>>(dec_emb, target_chunk, 512, wf16 + U_WFEED, bih_d, bhh_d, oscr + S_GFEED, 4096);

  // fused encoder: one launch per step (both directions)
  for (int t = 0; t < 64; ++t){
    k_enc_step<<<dim3(16,4,2), 256, 0, stream>>>(wf16, ws, oscr, t);
  }

  k_concat<<<256, 256, 0, stream>>>(ws);
  // A-attn = all_hidden @ Wa^T + ba via MFMA (MODE 0, K=1024)
  k_proj<0><<<dim3(8,16), 256, 0, stream>>>(ws + O_ALLH, nullptr, 1024, wf16 + U_WA, ba, nullptr, ws + O_AATT, 1024);

  // decoder: attention kernel fuses pointwise of previous step; MFMA gate GEMM
  const _Float16* wdec = wf16 + 2097152u;
  for (int t = 0; t < 64; ++t){
    k_attn<<<32, 256, 0, stream>>>(ws, oscr, t);
    k_dec_gemm<<<dim3(64,4), 256, 0, stream>>>(wdec, ws);
  }
  // finalize: pw_last + cvtA in one launch
  k_fin<<<128, 256, 0, stream>>>(ws, oscr);

  // vocab projection + fused argmax
  if (bigws){
    k_logits<<<dim3(16,250), 256, 0, stream>>>(
        (const _Float16*)(ws + O_ALLH), (const _Float16*)(ws + O_AATT),
        (const _Float16*)(ws + O_W1), bout, out, (unsigned long long*)(ws + O_PACK));
  } else {
    k_logits_fb<<<dim3(125,4), 512, 0, stream>>>(
        (const _Float16*)(ws + O_ALLH), (const _Float16*)(ws + O_AATT),
        Wout, bout, out, (unsigned long long*)(ws + O_PACK));
  }
  k_argmax<<<8, 256, 0, stream>>>((const unsigned long long*)(ws + O_PACK), out);
}

// Round 15
// 3309.716 us; speedup vs baseline: 1.1257x; 1.1257x over previous
//
#include <hip/hip_runtime.h>
#include <hip/hip_bf16.h>

#define BB 32
#define SS 64
#define TT 64
#define EE 512
#define HH 512
#define VV 32000

// ---- ws float offsets ----
#define O_C0    0u          // enc c parity0 [2dir][32][512]
#define O_C1    32768u      // enc c parity1
#define O_PENC  131072u     // enc partials parity A [dir][kp4][32b][2048]
#define O_PDEC  655360u     // enc partials parity B; dec partials [kp4][32][4096]
#define O_HD    65536u      // dec h [32][1024]
#define O_CD    98304u      // dec c
#define O_ALLH  1212416u    // all_hidden [32][64][1024]; later A1 (f16 hi)
#define O_AATT  3309568u    // A-attn [32][64][1024];    later A2 (f16 lo*2048)
#define O_HDEC  5406720u    // decoder hidden [32][64][1024]
#define O_PACK  7503872u    // 2048 u64 argmax packed
#define O_DA1   7507968u    // dec act f16 hi  [32][2048] (as f16)
#define O_DA2   7540736u    // dec act f16 lo*2048
#define O_W1    7573504u    // Wout f16 [32000][1024] (as f16) -- needs big ws
#define WS_NEED 95830016ull // bytes

// ---- d_out f32-scratch offsets (dead before k_logits) ----
#define S_GXF   0u          // [64][32][2048]
#define S_GXB   4194304u
#define S_GFEED 8388608u    // [64][32][4096]
#define U_BASE  17000000u   // f16 weights (as _Float16 offsets):
// [0,1M) Whh_f | [1M,2M) Whh_b | [2M,10.49M) WDEC [4096][2048]
// [10.49M,11.53M) Wih_f | [11.53M,12.58M) Wih_b | [12.58M,14.68M) WFEED [4096][512]
// [14.68M,15.73M) WA [1024][1024]
#define U_WIHF  10485760u
#define U_WIHB  11534336u
#define U_WFEED 12582912u
#define U_WA    14680064u
#define U_TOTAL 15728640u

typedef float f32x4 __attribute__((ext_vector_type(4)));
typedef _Float16 f16x8 __attribute__((ext_vector_type(8)));
typedef _Float16 f16x4 __attribute__((ext_vector_type(4)));

__device__ __forceinline__ float sigm_(float x){ return 1.0f/(1.0f + expf(-x)); }

__device__ __forceinline__ unsigned int fkey_(float f){
  unsigned int u = __float_as_uint(f);
  return (u & 0x80000000u) ? ~u : (u | 0x80000000u);
}

// XOR swizzle for f16 tiles with 64B rows (32 halves)
__device__ __forceinline__ int swz_(int row, int kb){
  return (row*64 + kb) ^ ((row & 7) << 4);
}

// ---------------- init ----------------
__global__ __launch_bounds__(256) void k_init(float* __restrict__ ws){
  int i = blockIdx.x*256 + threadIdx.x;
  if (i < 65536) ws[i] = 0.0f;   // both c-parity buffers
  if (i < 2048) ((unsigned long long*)(ws + O_PACK))[i] = 0ull;
}

// ---------------- weight f16 conversion (once) ----------------
__global__ __launch_bounds__(256) void k_cvtW(
    const float* __restrict__ Whh_f, const float* __restrict__ Whh_b,
    const float* __restrict__ Wih_d, const float* __restrict__ Whh_d,
    const float* __restrict__ Wih_f, const float* __restrict__ Wih_b,
    const float* __restrict__ Wa,
    _Float16* __restrict__ dst)
{
  int g = blockIdx.x*256 + threadIdx.x;
  unsigned idx = (unsigned)g*4u;
  if (idx >= U_TOTAL) return;
  f32x4 v;
  if (idx < 1048576u){
    v = *(const f32x4*)(Whh_f + idx);
  } else if (idx < 2097152u){
    v = *(const f32x4*)(Whh_b + (idx - 1048576u));
  } else if (idx < U_WIHF){
    unsigned j = idx - 2097152u;
    unsigned row = j >> 11, col = j & 2047u;
    const float* src = (col < 1024u) ? (Wih_d + (size_t)row*1536 + col)
                                     : (Whh_d + (size_t)row*1024 + (col - 1024u));
    v = *(const f32x4*)src;
  } else if (idx < U_WIHB){
    v = *(const f32x4*)(Wih_f + (idx - U_WIHF));
  } else if (idx < U_WFEED){
    v = *(const f32x4*)(Wih_b + (idx - U_WIHB));
  } else if (idx < U_WA){
    unsigned j = idx - U_WFEED;
    unsigned row = j >> 9, col = j & 511u;
    v = *(const f32x4*)(Wih_d + (size_t)row*1536 + 1024 + col);
  } else {
    v = *(const f32x4*)(Wa + (idx - U_WA));
  }
  f16x4 h;
  #pragma unroll
  for (int c = 0; c < 4; ++c) h[c] = (_Float16)v[c];
  *(f16x4*)(dst + idx) = h;
}

// ---------------- Wout f16 conversion (once, only if ws big enough) --------
__global__ __launch_bounds__(256) void k_cvtWout(
    const float* __restrict__ Wout, _Float16* __restrict__ W1)
{
  size_t i = ((size_t)blockIdx.x*256 + threadIdx.x)*8;
  f32x4 x0 = *(const f32x4*)(Wout + i);
  f32x4 x1 = *(const f32x4*)(Wout + i + 4);
  f16x4 h0, h1;
  #pragma unroll
  for (int c = 0; c < 4; ++c){ h0[c] = (_Float16)x0[c]; h1[c] = (_Float16)x1[c]; }
  *(f16x4*)(W1 + i)   = h0;
  *(f16x4*)(W1 + i+4) = h1;
}

// ---- projection GEMM via MFMA: C[M,N] = gather/plain A(fp32) * Wh(f16)^T + biases ----
// MODE 0: plain A rows (stride K).  MODE 1: enc gather.  MODE 2: feed gather (t==0 zero).
// Tile 128x128, BK=32, A split hi/lo*2048 in-kernel (2-product).
template<int MODE>
__global__ __launch_bounds__(256) void k_proj(
    const float* __restrict__ Asrc, const int* __restrict__ chunk, int K,
    const _Float16* __restrict__ Wh,
    const float* __restrict__ bias0, const float* __restrict__ bias1,
    float* __restrict__ C, int ldC)
{
  __shared__ char lds[49152];  // 2 bufs x (A1 8K | A2 8K | W 8K)
  int tid = threadIdx.x;
  int n0 = blockIdx.x*128, m0 = blockIdx.y*128;
  int lane = tid & 63, wave = tid >> 6;
  int wm = wave >> 1, wn = wave & 1;
  int lr = lane & 15, lg = lane >> 4;

  int s0 = tid*2, s1 = tid*2 + 1;
  int ar0 = s0 >> 2, as0 = s0 & 3;
  int ar1 = s1 >> 2, as1 = s1 & 3;

  const float* arp0; const float* arp1;
  {
    int m = m0 + ar0;
    if (MODE == 0){ arp0 = Asrc + (size_t)m*K + as0*8; }
    else if (MODE == 1){ int s = m >> 5, b = m & 31; arp0 = Asrc + (size_t)chunk[b*SS + s]*EE + as0*8; }
    else { int tt = m >> 5, b = m & 31; arp0 = tt ? (Asrc + (size_t)chunk[b*TT + (tt-1)]*EE + as0*8) : nullptr; }
    m = m0 + ar1;
    if (MODE == 0){ arp1 = Asrc + (size_t)m*K + as1*8; }
    else if (MODE == 1){ int s = m >> 5, b = m & 31; arp1 = Asrc + (size_t)chunk[b*SS + s]*EE + as1*8; }
    else { int tt = m >> 5, b = m & 31; arp1 = tt ? (Asrc + (size_t)chunk[b*TT + (tt-1)]*EE + as1*8) : nullptr; }
  }
  const _Float16* wp0 = Wh + (size_t)(n0 + ar0)*K + as0*8;
  const _Float16* wp1 = Wh + (size_t)(n0 + ar1)*K + as1*8;

  f32x4 accH[4][4], accM[4][4];
  #pragma unroll
  for (int i = 0; i < 4; ++i)
    #pragma unroll
    for (int j = 0; j < 4; ++j){
      f32x4 z; z[0]=z[1]=z[2]=z[3]=0.f;
      accH[i][j] = z; accM[i][j] = z;
    }

  f32x4 zz; zz[0]=zz[1]=zz[2]=zz[3]=0.f;
  f32x4 a0a, a0b, a1a, a1b;
  uint4 rw0, rw1;
  a0a = arp0 ? *(const f32x4*)(arp0)     : zz;
  a0b = arp0 ? *(const f32x4*)(arp0 + 4) : zz;
  a1a = arp1 ? *(const f32x4*)(arp1)     : zz;
  a1b = arp1 ? *(const f32x4*)(arp1 + 4) : zz;
  rw0 = *(const uint4*)wp0;
  rw1 = *(const uint4*)wp1;

  int kiters = K >> 5;
  for (int kt = 0; kt < kiters; ++kt){
    char* base = lds + (kt & 1)*24576;
    char* A1t = base, *A2t = base + 8192, *Wt = base + 16384;
    f16x8 h0, l0, h1, l1;
    #pragma unroll
    for (int c = 0; c < 4; ++c){
      float x = a0a[c]; _Float16 hh = (_Float16)x;
      h0[c] = hh; l0[c] = (_Float16)((x - (float)hh)*2048.0f);
      x = a0b[c]; hh = (_Float16)x;
      h0[4+c] = hh; l0[4+c] = (_Float16)((x - (float)hh)*2048.0f);
      x = a1a[c]; hh = (_Float16)x;
      h1[c] = hh; l1[c] = (_Float16)((x - (float)hh)*2048.0f);
      x = a1b[c]; hh = (_Float16)x;
      h1[4+c] = hh; l1[4+c] = (_Float16)((x - (float)hh)*2048.0f);
    }
    *(f16x8*)(A1t + swz_(ar0, as0*16)) = h0;
    *(f16x8*)(A2t + swz_(ar0, as0*16)) = l0;
    *(f16x8*)(A1t + swz_(ar1, as1*16)) = h1;
    *(f16x8*)(A2t + swz_(ar1, as1*16)) = l1;
    *(uint4*)(Wt + swz_(ar0, as0*16)) = rw0;
    *(uint4*)(Wt + swz_(ar1, as1*16)) = rw1;
    __syncthreads();
    if (kt < kiters-1){
      int ko = (kt+1)*32;
      a0a = arp0 ? *(const f32x4*)(arp0 + ko)     : zz;
      a0b = arp0 ? *(const f32x4*)(arp0 + ko + 4) : zz;
      a1a = arp1 ? *(const f32x4*)(arp1 + ko)     : zz;
      a1b = arp1 ? *(const f32x4*)(arp1 + ko + 4) : zz;
      rw0 = *(const uint4*)(wp0 + ko);
      rw1 = *(const uint4*)(wp1 + ko);
    }
    f16x8 wf[4];
    #pragma unroll
    for (int nf = 0; nf < 4; ++nf)
      wf[nf] = *(const f16x8*)(Wt + swz_(wn*64 + nf*16 + lr, lg*16));
    #pragma unroll
    for (int mf = 0; mf < 4; ++mf){
      int ad = swz_(wm*64 + mf*16 + lr, lg*16);
      f16x8 a1f = *(const f16x8*)(A1t + ad);
      f16x8 a2f = *(const f16x8*)(A2t + ad);
      #pragma unroll
      for (int nf = 0; nf < 4; ++nf){
        accH[mf][nf] = __builtin_amdgcn_mfma_f32_16x16x32_f16(a1f, wf[nf], accH[mf][nf], 0, 0, 0);
        accM[mf][nf] = __builtin_amdgcn_mfma_f32_16x16x32_f16(a2f, wf[nf], accM[mf][nf], 0, 0, 0);
      }
    }
    __syncthreads();
  }

  const float rs = 1.0f/2048.0f;
  float bb[4];
  #pragma unroll
  for (int nf = 0; nf < 4; ++nf){
    int n = n0 + wn*64 + nf*16 + lr;
    bb[nf] = bias0[n] + (bias1 ? bias1[n] : 0.0f);
  }
  #pragma unroll
  for (int mf = 0; mf < 4; ++mf){
    #pragma unroll
    for (int r = 0; r < 4; ++r){
      int m = m0 + wm*64 + mf*16 + lg*4 + r;
      #pragma unroll
      for (int nf = 0; nf < 4; ++nf){
        int n = n0 + wn*64 + nf*16 + lr;
        C[(size_t)m*ldC + n] = accH[mf][nf][r] + accM[mf][nf][r]*rs + bb[nf];
      }
    }
  }
}

// ---------------- fused encoder step (f16 Whh) ----------------
// grid (16 sub, 4 kp, 2 dir) x 256.  Partials parity: read (t&1? PDEC:PENC), write other.
__global__ __launch_bounds__(256) void k_enc_step(
    const _Float16* __restrict__ wenc,
    float* __restrict__ ws, const float* __restrict__ oscr, int t)
{
  __shared__ float hl[128*36];
  __shared__ float Wt[32*132];
  int sub = blockIdx.x, kp = blockIdx.y, dir = blockIdx.z;
  int tid = threadIdx.x;
  int s = dir ? (63 - t) : t;
  int p = t & 1;
  const float* gx  = oscr + (dir ? S_GXB : S_GXF);
  const float* prd = ws + (p ? O_PDEC : O_PENC) + dir*262144u;
  const float* cin = ws + O_C0 + p*32768u + dir*16384u;
  float* cout = ws + O_C0 + (p^1)*32768u + dir*16384u;

  {
    int ug = tid & 31, bg = tid >> 5;
    int ul0 = ug*4;
    int u0 = kp*128 + ul0;
    #pragma unroll
    for (int j = 0; j < 4; ++j){
      int b = bg*4 + j;
      size_t gbase = (size_t)(s*32 + b)*2048u;
      f32x4 g0 = *(const f32x4*)&gx[gbase + u0];
      f32x4 g1 = *(const f32x4*)&gx[gbase + 512 + u0];
      f32x4 g2 = *(const f32x4*)&gx[gbase + 1024 + u0];
      f32x4 g3 = *(const f32x4*)&gx[gbase + 1536 + u0];
      if (t > 0){
        #pragma unroll
        for (int kq = 0; kq < 4; ++kq){
          const float* pp = prd + kq*65536u + (size_t)b*2048u;
          g0 += *(const f32x4*)&pp[u0];
          g1 += *(const f32x4*)&pp[512 + u0];
          g2 += *(const f32x4*)&pp[1024 + u0];
          g3 += *(const f32x4*)&pp[1536 + u0];
        }
      }
      f32x4 c = *(const f32x4*)&cin[b*512 + u0];
      f32x4 cn, hn;
      #pragma unroll
      for (int e = 0; e < 4; ++e){
        float cc = sigm_(g1[e])*c[e] + sigm_(g0[e])*tanhf(g2[e]);
        float hh = sigm_(g3[e])*tanhf(cc);
        cn[e] = cc; hn[e] = hh;
        hl[(ul0+e)*36 + b] = hh;
      }
      if (sub == 0){
        *(f32x4*)&cout[b*512 + u0] = cn;
        *(f32x4*)&ws[O_ALLH + (size_t)(b*64 + s)*1024u + dir*512 + u0] = hn;
      }
    }
  }
  __syncthreads();
  if (t == 63) return;

  const _Float16* W = wenc + dir*1048576u;
  float* P = ws + (p ? O_PENC : O_PDEC) + dir*262144u + kp*65536u;
  int rg2 = tid & 31, bg2 = tid >> 5;
  int wrow = tid & 127, whalf = tid >> 7;
  float acc[4][4] = {};
  for (int kt = 0; kt < 4; ++kt){
    #pragma unroll
    for (int i = 0; i < 4; ++i){
      int chunk = whalf*4 + i;
      int grow = sub*128 + wrow;
      f16x4 v = *(const f16x4*)&W[(size_t)grow*512 + kp*128 + kt*32 + chunk*4];
      Wt[(chunk*4+0)*132 + wrow] = (float)v[0];
      Wt[(chunk*4+1)*132 + wrow] = (float)v[1];
      Wt[(chunk*4+2)*132 + wrow] = (float)v[2];
      Wt[(chunk*4+3)*132 + wrow] = (float)v[3];
    }
    __syncthreads();
    #pragma unroll 8
    for (int kk = 0; kk < 32; ++kk){
      f32x4 wv = *(const f32x4*)&Wt[kk*132 + rg2*4];
      f32x4 hv = *(const f32x4*)&hl[(kt*32+kk)*36 + bg2*4];
      #pragma unroll
      for (int i = 0; i < 4; ++i)
        #pragma unroll
        for (int j = 0; j < 4; ++j)
          acc[i][j] = fmaf(wv[i], hv[j], acc[i][j]);
    }
    __syncthreads();
  }
  #pragma unroll
  for (int j = 0; j < 4; ++j){
    int b = bg2*4 + j;
    f32x4 v; v[0]=acc[0][j]; v[1]=acc[1][j]; v[2]=acc[2][j]; v[3]=acc[3][j];
    *(f32x4*)&P[(size_t)b*2048u + sub*128 + rg2*4] = v;
  }
}

// ---------------- decoder state init ----------------
__global__ __launch_bounds__(256) void k_concat(float* __restrict__ ws){
  int i = blockIdx.x*256 + threadIdx.x;   // 0..65535
  int which = i >> 15;
  int idx = i & 32767;
  int b = idx >> 10, u = idx & 1023;
  int dir = (u >= 512);
  int uu = u & 511;
  float v;
  if (which == 0){
    int s = dir ? 0 : 63;
    v = ws[O_ALLH + (size_t)(b*64 + s)*1024u + u];
  } else {
    v = ws[O_C0 + dir*16384u + b*512 + uu];
  }
  ws[(which ? O_CD : O_HD) + b*1024 + u] = v;
}

// ---------------- decoder gate GEMM via MFMA (2-product split-A, f16 W) ----
// grid (64 nb, 4 kp) x 256 (4 waves). K-slice 512, BN=64.
__global__ __launch_bounds__(256) void k_dec_gemm(
    const _Float16* __restrict__ wdec, float* __restrict__ ws)
{
  __shared__ char lds[16384];   // 2 bufs x (A1 2K | A2 2K | W 4K)
  int nb = blockIdx.x, kp = blockIdx.y;
  int tid = threadIdx.x;
  int lane = tid & 63, w = tid >> 6;
  int lr = lane & 15, lg = lane >> 4;
  const _Float16* A1g = (const _Float16*)(ws + O_DA1);
  const _Float16* A2g = (const _Float16*)(ws + O_DA2);

  int aslot = tid & 127;
  int isA2  = tid >> 7;
  int arow = aslot >> 2, aseg = aslot & 3;
  int wrow = tid >> 2, wseg = tid & 3;
  const _Float16* asrc = (isA2 ? A2g : A1g) + (size_t)arow*2048u + kp*512 + aseg*8;
  const _Float16* wsrc = wdec + (size_t)(nb*64 + wrow)*2048u + kp*512 + wseg*8;

  f32x4 accH[2], accM[2];
  #pragma unroll
  for (int i = 0; i < 2; ++i){ f32x4 z; z[0]=z[1]=z[2]=z[3]=0.f; accH[i]=z; accM[i]=z; }

  uint4 rA = *(const uint4*)(asrc);
  uint4 rW = *(const uint4*)(wsrc);

  for (int kt = 0; kt < 16; ++kt){
    int cur = kt & 1;
    char* base = lds + cur*8192;
    *(uint4*)(base + (isA2 ? 2048 : 0) + swz_(arow, aseg*16)) = rA;
    *(uint4*)(base + 4096 + swz_(wrow, wseg*16)) = rW;
    __syncthreads();
    if (kt < 15){
      rA = *(const uint4*)(asrc + (kt+1)*32);
      rW = *(const uint4*)(wsrc + (kt+1)*32);
    }
    char* A1t = base, *A2t = base + 2048, *Wt = base + 4096;
    f16x8 wf = *(const f16x8*)(Wt + swz_(w*16 + lr, lg*16));
    #pragma unroll
    for (int mf = 0; mf < 2; ++mf){
      f16x8 a1 = *(const f16x8*)(A1t + swz_(mf*16 + lr, lg*16));
      f16x8 a2 = *(const f16x8*)(A2t + swz_(mf*16 + lr, lg*16));
      accH[mf] = __builtin_amdgcn_mfma_f32_16x16x32_f16(a1, wf, accH[mf], 0, 0, 0);
      accM[mf] = __builtin_amdgcn_mfma_f32_16x16x32_f16(a2, wf, accM[mf], 0, 0, 0);
    }
    __syncthreads();
  }
  const float rs = 1.0f/2048.0f;
  float* P = ws + O_PDEC + (size_t)kp*131072u;
  #pragma unroll
  for (int mf = 0; mf < 2; ++mf)
    #pragma unroll
    for (int r = 0; r < 4; ++r){
      int b = mf*16 + lg*4 + r;
      int n = nb*64 + w*16 + lr;
      P[(size_t)b*4096u + n] = accH[mf][r] + accM[mf][r]*rs;
    }
}

// ---------------- attention step (fuses pointwise of step t-1), 32 blocks ----------
__global__ __launch_bounds__(256) void k_attn(float* __restrict__ ws,
                                              const float* __restrict__ oscr, int t){
  __shared__ float hlq[1024];
  __shared__ float part[64][5];
  __shared__ float sc[64];
  __shared__ float atn[64];
  __shared__ float dsh;
  int b = blockIdx.x, tid = threadIdx.x;
  float* hd = ws + O_HD;
  float* cd = ws + O_CD;
  _Float16* DA1 = (_Float16*)(ws + O_DA1);
  _Float16* DA2 = (_Float16*)(ws + O_DA2);
  if (t > 0){
    const float* gfd = oscr + S_GFEED + (size_t)((t-1)*32 + b)*4096u;
    const float* pd = ws + O_PDEC;
    for (int u = tid; u < 1024; u += 256){
      float g0 = gfd[u], g1 = gfd[1024+u], g2 = gfd[2048+u], g3 = gfd[3072+u];
      #pragma unroll
      for (int kp = 0; kp < 4; ++kp){
        const float* p = pd + (size_t)kp*131072u + (size_t)b*4096u;
        g0 += p[u]; g1 += p[1024+u]; g2 += p[2048+u]; g3 += p[3072+u];
      }
      float c = cd[b*1024 + u];
      c = sigm_(g1)*c + sigm_(g0)*tanhf(g2);
      float h = sigm_(g3)*tanhf(c);
      cd[b*1024+u] = c; hd[b*1024+u] = h; hlq[u] = h;
      ws[O_HDEC + (size_t)(b*64 + (t-1))*1024u + u] = h;
      _Float16 hi = (_Float16)h;
      DA1[(size_t)b*2048u + 1024 + u] = hi;
      DA2[(size_t)b*2048u + 1024 + u] = (_Float16)((h - (float)hi)*2048.0f);
    }
  } else {
    for (int u = tid; u < 1024; u += 256){
      float h = hd[b*1024 + u];
      hlq[u] = h;
      _Float16 hi = (_Float16)h;
      DA1[(size_t)b*2048u + 1024 + u] = hi;
      DA2[(size_t)b*2048u + 1024 + u] = (_Float16)((h - (float)hi)*2048.0f);
    }
  }
  __syncthreads();
  {
    int s = tid >> 2, p = tid & 3;
    const float* Ar = ws + O_AATT + (size_t)(b*64 + s)*1024u + p*256;
    const float* hp = &hlq[p*256];
    float sum = 0.f;
    #pragma unroll 8
    for (int k4 = 0; k4 < 64; ++k4){
      float4 a = *(const float4*)&Ar[k4*4];
      float4 h4 = *(const float4*)&hp[k4*4];
      sum = fmaf(a.x,h4.x, fmaf(a.y,h4.y, fmaf(a.z,h4.z, fmaf(a.w,h4.w, sum))));
    }
    part[s][p] = sum;
  }
  __syncthreads();
  if (tid < 64) sc[tid] = part[tid][0] + part[tid][1] + part[tid][2] + part[tid][3];
  __syncthreads();
  if (tid < 64){
    float m = sc[0];
    #pragma unroll
    for (int i = 1; i < 64; ++i) m = fmaxf(m, sc[i]);
    atn[tid] = expf(sc[tid] - m);
  }
  __syncthreads();
  if (tid == 0){
    float d = 0.f;
    #pragma unroll
    for (int i = 0; i < 64; ++i) d += atn[i];
    dsh = 1.0f/d;
  }
  __syncthreads();
  {
    float rd = dsh;
    float ax=0.f, ay=0.f, az=0.f, aw=0.f;
    const float* ah = ws + O_ALLH + (size_t)(b*64)*1024u + tid*4;
    for (int s2 = 0; s2 < 64; ++s2){
      float a = atn[s2];
      float4 v = *(const float4*)&ah[(size_t)s2*1024u];
      ax = fmaf(a, v.x, ax); ay = fmaf(a, v.y, ay);
      az = fmaf(a, v.z, az); aw = fmaf(a, v.w, aw);
    }
    float o[4] = {ax*rd, ay*rd, az*rd, aw*rd};
    #pragma unroll
    for (int j = 0; j < 4; ++j){
      int u = tid*4 + j;
      _Float16 hi = (_Float16)o[j];
      DA1[(size_t)b*2048u + u] = hi;
      DA2[(size_t)b*2048u + u] = (_Float16)((o[j] - (float)hi)*2048.0f);
    }
  }
}

// ---------------- finalize: pw_last (t=63) + cvtA, one launch, 128 blocks ----
__global__ __launch_bounds__(256) void k_fin(float* __restrict__ ws,
                                             const float* __restrict__ oscr){
  int bid = blockIdx.x, tid = threadIdx.x;
  if ((bid & 3) == 3){
    int b = bid >> 2;
    const float* gfd = oscr + S_GFEED + (size_t)(63*32 + b)*4096u;
    const float* pd = ws + O_PDEC;
    for (int q = 0; q < 4; ++q){
      int u = q*256 + tid;
      float g0 = gfd[u], g1 = gfd[1024+u], g2 = gfd[2048+u], g3 = gfd[3072+u];
      #pragma unroll
      for (int kp = 0; kp < 4; ++kp){
        const float* p = pd + (size_t)kp*131072u + (size_t)b*4096u;
        g0 += p[u]; g1 += p[1024+u]; g2 += p[2048+u]; g3 += p[3072+u];
      }
      float c = ws[O_CD + b*1024 + u];
      c = sigm_(g1)*c + sigm_(g0)*tanhf(g2);
      float h = sigm_(g3)*tanhf(c);
      ws[O_HDEC + (size_t)(b*64 + 63)*1024u + u] = h;
    }
  }
  __syncthreads();
  const float* src = ws + O_HDEC;
  _Float16* A1 = (_Float16*)(ws + O_ALLH);
  _Float16* A2 = (_Float16*)(ws + O_AATT);
  for (int rep = 0; rep < 8; ++rep){
    int i = bid*16384 + (rep*256 + tid)*8;
    f32x4 x0 = *(const f32x4*)&src[i];
    f32x4 x1 = *(const f32x4*)&src[i+4];
    f16x4 h0, h1, l0, l1;
    #pragma unroll
    for (int c = 0; c < 4; ++c){
      _Float16 a = (_Float16)x0[c];
      h0[c] = a; l0[c] = (_Float16)((x0[c] - (float)a)*2048.0f);
      _Float16 bq = (_Float16)x1[c];
      h1[c] = bq; l1[c] = (_Float16)((x1[c] - (float)bq)*2048.0f);
    }
    *(f16x4*)&A1[i]   = h0;
    *(f16x4*)&A1[i+4] = h1;
    *(f16x4*)&A2[i]   = l0;
    *(f16x4*)&A2[i+4] = l1;
  }
}

// ---------------- logits (primary): 2-product f16 MFMA, pre-split W ---------
// grid (16 m, 250 n) x 256 (4 waves 2m x 2n). BM=BN=128, BK=32, dbuf LDS.
// m fastest => 16 consecutive blocks share one W-panel (L3 reuse window).
__global__ __launch_bounds__(256) void k_logits(
    const _Float16* __restrict__ A1, const _Float16* __restrict__ A2,
    const _Float16* __restrict__ W1, const float* __restrict__ bout,
    float* __restrict__ out, unsigned long long* __restrict__ pk)
{
  __shared__ char lds[49152];  // 2 bufs x (A1 8K | A2 8K | W 8K)
  int tid = threadIdx.x;
  int n0 = blockIdx.y*128, m0 = blockIdx.x*128;
  int lane = tid & 63, wave = tid >> 6;
  int wm = wave >> 1, wn = wave & 1;
  int lr = lane & 15, lg = lane >> 4;

  int s0 = tid*2, s1 = tid*2 + 1;
  int ar0 = s0 >> 2, as0 = s0 & 3;
  int ar1 = s1 >> 2, as1 = s1 & 3;
  const _Float16* a1p0 = A1 + (size_t)(m0 + ar0)*1024u + as0*8;
  const _Float16* a1p1 = A1 + (size_t)(m0 + ar1)*1024u + as1*8;
  const _Float16* a2p0 = A2 + (size_t)(m0 + ar0)*1024u + as0*8;
  const _Float16* a2p1 = A2 + (size_t)(m0 + ar1)*1024u + as1*8;
  const _Float16* wp0  = W1 + (size_t)(n0 + ar0)*1024u + as0*8;
  const _Float16* wp1  = W1 + (size_t)(n0 + ar1)*1024u + as1*8;

  f32x4 accH[4][4], accM[4][4];
  #pragma unroll
  for (int i = 0; i < 4; ++i)
    #pragma unroll
    for (int j = 0; j < 4; ++j){
      f32x4 z; z[0]=z[1]=z[2]=z[3]=0.f;
      accH[i][j] = z; accM[i][j] = z;
    }

  uint4 r10, r11, r20, r21, rw0, rw1;
  r10 = *(const uint4*)a1p0; r11 = *(const uint4*)a1p1;
  r20 = *(const uint4*)a2p0; r21 = *(const uint4*)a2p1;
  rw0 = *(const uint4*)wp0;  rw1 = *(const uint4*)wp1;

  for (int kt = 0; kt < 32; ++kt){
    int cur = kt & 1;
    char* base = lds + cur*24576;
    char* A1t = base, *A2t = base + 8192, *Wt = base + 16384;
    *(uint4*)(A1t + swz_(ar0, as0*16)) = r10;
    *(uint4*)(A1t + swz_(ar1, as1*16)) = r11;
    *(uint4*)(A2t + swz_(ar0, as0*16)) = r20;
    *(uint4*)(A2t + swz_(ar1, as1*16)) = r21;
    *(uint4*)(Wt  + swz_(ar0, as0*16)) = rw0;
    *(uint4*)(Wt  + swz_(ar1, as1*16)) = rw1;
    __syncthreads();
    if (kt < 31){
      int ko = (kt+1)*32;
      r10 = *(const uint4*)(a1p0 + ko); r11 = *(const uint4*)(a1p1 + ko);
      r20 = *(const uint4*)(a2p0 + ko); r21 = *(const uint4*)(a2p1 + ko);
      rw0 = *(const uint4*)(wp0 + ko);  rw1 = *(const uint4*)(wp1 + ko);
    }
    f16x8 wf[4];
    #pragma unroll
    for (int nf = 0; nf < 4; ++nf)
      wf[nf] = *(const f16x8*)(Wt + swz_(wn*64 + nf*16 + lr, lg*16));
    #pragma unroll
    for (int mf = 0; mf < 4; ++mf){
      int ad = swz_(wm*64 + mf*16 + lr, lg*16);
      f16x8 a1f = *(const f16x8*)(A1t + ad);
      f16x8 a2f = *(const f16x8*)(A2t + ad);
      #pragma unroll
      for (int nf = 0; nf < 4; ++nf){
        accH[mf][nf] = __builtin_amdgcn_mfma_f32_16x16x32_f16(a1f, wf[nf], accH[mf][nf], 0, 0, 0);
        accM[mf][nf] = __builtin_amdgcn_mfma_f32_16x16x32_f16(a2f, wf[nf], accM[mf][nf], 0, 0, 0);
      }
    }
    __syncthreads();
  }

  const float rs = 1.0f/2048.0f;
  float bb[4];
  #pragma unroll
  for (int nf = 0; nf < 4; ++nf) bb[nf] = bout[n0 + wn*64 + nf*16 + lr];
  #pragma unroll
  for (int mf = 0; mf < 4; ++mf){
    #pragma unroll
    for (int r = 0; r < 4; ++r){
      int m = m0 + wm*64 + mf*16 + lg*4 + r;
      unsigned long long bk = 0ull;
      #pragma unroll
      for (int nf = 0; nf < 4; ++nf){
        int n = n0 + wn*64 + nf*16 + lr;
        float val = accH[mf][nf][r] + accM[mf][nf][r]*rs + bb[nf];
        __builtin_nontemporal_store(val, &out[(size_t)m*VV + n]);
        unsigned long long p = ((unsigned long long)fkey_(val) << 32) | (unsigned int)(~(unsigned int)n);
        if (p > bk) bk = p;
      }
      #pragma unroll
      for (int off = 1; off < 16; off <<= 1){
        unsigned long long o = __shfl_xor(bk, off, 64);
        if (o > bk) bk = o;
      }
      if (lr == 0) atomicMax(&pk[m], bk);
    }
  }
}

// ---------------- logits fallback (small ws): in-kernel split, 3 products ----
__global__ __launch_bounds__(512) void k_logits_fb(
    const _Float16* __restrict__ A1, const _Float16* __restrict__ A2,
    const float* __restrict__ Wout, const float* __restrict__ bout,
    float* __restrict__ out, unsigned long long* __restrict__ pk)
{
  __shared__ char lds[49152];
  char* A1t = lds;
  char* A2t = lds + 8192;
  char* W1t = lds + 16384;
  char* W2t = lds + 32768;
  int tid = threadIdx.x;
  int n0 = blockIdx.x*256;
  int lane = tid & 63, wave = tid >> 6;
  int wm = wave >> 2, wn = wave & 3;
  int lr = lane & 15, lg = lane >> 4;

  int arow = tid >> 2, aseg = tid & 3;
  int wrow = tid >> 1, wseg = tid & 1;
  const float* wp = Wout + (size_t)(n0 + wrow)*1024u + wseg*16;

  float bb[4];
  #pragma unroll
  for (int nf = 0; nf < 4; ++nf) bb[nf] = bout[n0 + wn*64 + nf*16 + lr];
  const float rs = 1.0f/2048.0f;

  for (int mi = 0; mi < 4; ++mi){
    int m0 = (blockIdx.y*4 + mi)*128;
    const _Float16* a1p = A1 + (size_t)(m0 + arow)*1024u + aseg*8;
    const _Float16* a2p = A2 + (size_t)(m0 + arow)*1024u + aseg*8;

    f32x4 accH[4][4], accM[4][4];
    #pragma unroll
    for (int i = 0; i < 4; ++i)
      #pragma unroll
      for (int j = 0; j < 4; ++j){
        f32x4 z; z[0]=z[1]=z[2]=z[3]=0.f;
        accH[i][j] = z; accM[i][j] = z;
      }

    for (int k0 = 0; k0 < 1024; k0 += 32){
      uint4 av1 = *(const uint4*)(a1p + k0);
      uint4 av2 = *(const uint4*)(a2p + k0);
      f32x4 wv[4];
      #pragma unroll
      for (int i = 0; i < 4; ++i) wv[i] = *(const f32x4*)(wp + k0 + i*4);
      __syncthreads();
      *(uint4*)(A1t + swz_(arow, aseg*16)) = av1;
      *(uint4*)(A2t + swz_(arow, aseg*16)) = av2;
      f16x8 hi[2], lo[2];
      #pragma unroll
      for (int i = 0; i < 2; ++i)
        #pragma unroll
        for (int c = 0; c < 8; ++c){
          float x = wv[i*2 + (c>>2)][c&3];
          _Float16 h = (_Float16)x;
          hi[i][c] = h;
          lo[i][c] = (_Float16)((x - (float)h)*2048.0f);
        }
      *(f16x8*)(W1t + swz_(wrow, wseg*32 +  0)) = hi[0];
      *(f16x8*)(W1t + swz_(wrow, wseg*32 + 16)) = hi[1];
      *(f16x8*)(W2t + swz_(wrow, wseg*32 +  0)) = lo[0];
      *(f16x8*)(W2t + swz_(wrow, wseg*32 + 16)) = lo[1];
      __syncthreads();
      f16x8 w1f[4], w2f[4];
      #pragma unroll
      for (int nf = 0; nf < 4; ++nf){
        int ad = swz_(wn*64 + nf*16 + lr, lg*16);
        w1f[nf] = *(const f16x8*)(W1t + ad);
        w2f[nf] = *(const f16x8*)(W2t + ad);
      }
      #pragma unroll
      for (int mf = 0; mf < 4; ++mf){
        int ad = swz_(wm*64 + mf*16 + lr, lg*16);
        f16x8 a1f = *(const f16x8*)(A1t + ad);
        f16x8 a2f = *(const f16x8*)(A2t + ad);
        #pragma unroll
        for (int nf = 0; nf < 4; ++nf){
          accH[mf][nf] = __builtin_amdgcn_mfma_f32_16x16x32_f16(a1f, w1f[nf], accH[mf][nf], 0, 0, 0);
          accM[mf][nf] = __builtin_amdgcn_mfma_f32_16x16x32_f16(a1f, w2f[nf], accM[mf][nf], 0, 0, 0);
          accM[mf][nf] = __builtin_amdgcn_mfma_f32_16x16x32_f16(a2f, w1f[nf], accM[mf][nf], 0, 0, 0);
        }
      }
    }

    #pragma unroll
    for (int mf = 0; mf < 4; ++mf){
      #pragma unroll
      for (int r = 0; r < 4; ++r){
        int m = m0 + wm*64 + mf*16 + lg*4 + r;
        unsigned long long bk = 0ull;
        #pragma unroll
        for (int nf = 0; nf < 4; ++nf){
          int n = n0 + wn*64 + nf*16 + lr;
          float val = accH[mf][nf][r] + accM[mf][nf][r]*rs + bb[nf];
          __builtin_nontemporal_store(val, &out[(size_t)m*VV + n]);
          unsigned long long p = ((unsigned long long)fkey_(val) << 32) | (unsigned int)(~(unsigned int)n);
          if (p > bk) bk = p;
        }
        #pragma unroll
        for (int off = 1; off < 16; off <<= 1){
          unsigned long long o = __shfl_xor(bk, off, 64);
          if (o > bk) bk = o;
        }
        if (lr == 0) atomicMax(&pk[m], bk);
      }
    }
  }
}

__global__ __launch_bounds__(256) void k_argmax(
    const unsigned long long* __restrict__ pk, float* __restrict__ out)
{
  int i = blockIdx.x*256 + threadIdx.x;
  if (i < 2048){
    unsigned int low = (unsigned int)(pk[i] & 0xFFFFFFFFull);
    unsigned int col = ~low;
    out[(size_t)BB*TT*VV + i] = (float)col;
  }
}

extern "C" void kernel_launch(void* const* d_in, const int* in_sizes, int n_in,
                              void* d_out, int out_size, void* d_ws, size_t ws_size,
                              hipStream_t stream)
{
  const int*   input_chunk  = (const int*)d_in[0];
  const int*   target_chunk = (const int*)d_in[1];
  const float* enc_emb = (const float*)d_in[2];
  const float* dec_emb = (const float*)d_in[3];
  const float* Wih_f = (const float*)d_in[4];
  const float* Whh_f = (const float*)d_in[5];
  const float* bih_f = (const float*)d_in[6];
  const float* bhh_f = (const float*)d_in[7];
  const float* Wih_b = (const float*)d_in[8];
  const float* Whh_b = (const float*)d_in[9];
  const float* bih_b = (const float*)d_in[10];
  const float* bhh_b = (const float*)d_in[11];
  const float* Wih_d = (const float*)d_in[12];
  const float* Whh_d = (const float*)d_in[13];
  const float* bih_d = (const float*)d_in[14];
  const float* bhh_d = (const float*)d_in[15];
  const float* Wa   = (const float*)d_in[16];
  const float* ba   = (const float*)d_in[17];
  const float* Wout = (const float*)d_in[18];
  const float* bout = (const float*)d_in[19];
  float* ws = (float*)d_ws;
  float* out = (float*)d_out;
  float* oscr = (float*)d_out;
  _Float16* wf16 = (_Float16*)(oscr + U_BASE);
  bool bigws = (ws_size >= WS_NEED);

  k_init<<<256, 256, 0, stream>>>(ws);
  k_cvtW<<<15360, 256, 0, stream>>>(Whh_f, Whh_b, Wih_d, Whh_d, Wih_f, Wih_b, Wa, wf16);
  if (bigws)
    k_cvtWout<<<16000, 256, 0, stream>>>(Wout, (_Float16*)(ws + O_W1));

  // batched input projections via MFMA (biases folded) into d_out scratch
  k_proj<1><<<dim3(16,16), 256, 0, stream>>>(enc_emb, input_chunk, 512, wf16 + U_WIHF, bih_f, bhh_f, oscr + S_GXF, 2048);
  k_proj<1><<<dim3(16,16), 256, 0, stream>>>(enc_emb, input_chunk, 512, wf16 + U_WIHB, bih_b, bhh_b, oscr + S_GXB, 2048);
  k_proj<2><<<dim3(32,16), 256, 0, stream>>>(dec_emb, target_chunk, 512, wf16 + U_WFEED, bih_d, bhh_d, oscr + S_GFEED, 4096);

  // fused encoder: one launch per step (both directions)
  for (int t = 0; t < 64; ++t){
    k_enc_step<<<dim3(16,4,2), 256, 0, stream>>>(wf16, ws, oscr, t);
  }

  k_concat<<<256, 256, 0, stream>>>(ws);
  // A-attn = all_hidden @ Wa^T + ba via MFMA (MODE 0, K=1024)
  k_proj<0><<<dim3(8,16), 256, 0, stream>>>(ws + O_ALLH, nullptr, 1024, wf16 + U_WA, ba, nullptr, ws + O_AATT, 1024);

  // decoder: attention kernel fuses pointwise of previous step; MFMA gate GEMM
  const _Float16* wdec = wf16 + 2097152u;
  for (int t = 0; t < 64; ++t){
    k_attn<<<32, 256, 0, stream>>>(ws, oscr, t);
    k_dec_gemm<<<dim3(64,4), 256, 0, stream>>>(wdec, ws);
  }
  // finalize: pw_last + cvtA in one launch
  k_fin<<<128, 256, 0, stream>>>(ws, oscr);

  // vocab projection + fused argmax
  if (bigws){
    k_logits<<<dim3(16,250), 256, 0, stream>>>(
        (const _Float16*)(ws + O_ALLH), (const _Float16*)(ws + O_AATT),
        (const _Float16*)(ws + O_W1), bout, out, (unsigned long long*)(ws + O_PACK));
  } else {
    k_logits_fb<<<dim3(125,4), 512, 0, stream>>>(
        (const _Float16*)(ws + O_ALLH), (const _Float16*)(ws + O_AATT),
        Wout, bout, out, (unsigned long long*)(ws + O_PACK));
  }
  k_argmax<<<8, 256, 0, stream>>>((const unsigned long long*)(ws + O_PACK), out);
}